// Round 1
// baseline (2378.803 us; speedup 1.0000x reference)
//
#include <hip/hip_runtime.h>
#include <math.h>

#define EPSC   1e-6f
#define BNEPS  1e-5f
#define NSWEEP 8

#define NBLK_A   512
#define NHW      (NBLK_A * 8)       // 4096 half-waves
#define NMAT     16384              // B*C matrices
#define ROUNDS   (NMAT / NHW)       // 4

// workspace layout (float offsets)
#define OFF_BM      0
#define OFF_BMSQ    4096
#define OFF_BMISQ   8192
#define OFF_MEANSQ  12288
#define OFF_RMISQ   16384
#define OFF_SVEC    20480
#define OFF_PART1   32768                        // 256*4096  (kernel1 only)
#define OFF_GTBLK   32768                        // 512*4*1024 (overlaps PART1; disjoint in time)
#define OFF_SLLBLK  (32768 + 512*4*1024)         // 65536
#define OFF_GT2     (OFF_SLLBLK + 65536)         // 64*1024
// total ~2.26M floats ~ 8.7 MB

// ---------- device helpers ----------

// One-sided (Hestenes) Jacobi. Lane k of each 32-lane half-wave owns column k
// (32 registers). XOR-mask pairing: masks 1..31 cover all pairs per sweep and
// each mask is a perfect matching (disjoint pairs -> parallel rotations valid).
// Both lanes of a pair compute identical (c,s,t) from identical values.
__device__ __forceinline__ void jacobi32(float a[32], int k) {
    float alpha = 0.f;
#pragma unroll
    for (int i = 0; i < 32; ++i) alpha = fmaf(a[i], a[i], alpha);
    for (int sweep = 0; sweep < NSWEEP; ++sweep) {
        for (int m = 1; m < 32; ++m) {
            float q[32];
#pragma unroll
            for (int i = 0; i < 32; ++i) q[i] = __shfl_xor(a[i], m);
            float beta = __shfl_xor(alpha, m);
            float g0 = 0.f, g1 = 0.f, g2 = 0.f, g3 = 0.f;
#pragma unroll
            for (int i = 0; i < 32; i += 4) {
                g0 = fmaf(a[i+0], q[i+0], g0);
                g1 = fmaf(a[i+1], q[i+1], g1);
                g2 = fmaf(a[i+2], q[i+2], g2);
                g3 = fmaf(a[i+3], q[i+3], g3);
            }
            float gam = (g0 + g1) + (g2 + g3);
            bool isp = (k < (k ^ m));
            float aa = isp ? alpha : beta;   // ||a_p||^2
            float bb = isp ? beta  : alpha;  // ||a_q||^2
            float c, s, t;
            if (fabsf(gam) < 1e-30f) {
                c = 1.f; s = 0.f; t = 0.f;
            } else {
                float tau = (bb - aa) / (2.f * gam);
                t = copysignf(1.f, tau) / (fabsf(tau) + sqrtf(fmaf(tau, tau, 1.f)));
                c = rsqrtf(fmaf(t, t, 1.f));
                s = t * c;
            }
            float se = isp ? -s : s;
            float te = isp ? -t : t;
#pragma unroll
            for (int i = 0; i < 32; ++i) a[i] = fmaf(se, q[i], c * a[i]);
            alpha = fmaf(te, gam, alpha);    // alpha' = alpha -/+ t*gamma
        }
    }
}

// y = M v; M is 32x32 in LDS, 32-float blocks treated as columns (symmetric
// matrices stored row-major work identically). Broadcast reads: conflict-free.
__device__ __forceinline__ void matvec32(const float* M, const float v[32], float y[32]) {
#pragma unroll
    for (int i = 0; i < 32; ++i) y[i] = 0.f;
#pragma unroll
    for (int j = 0; j < 32; ++j) {
        const float4* col = (const float4*)(M + j * 32);
        float vj = v[j];
#pragma unroll
        for (int cc = 0; cc < 8; ++cc) {
            float4 r = col[cc];
            y[cc*4+0] = fmaf(vj, r.x, y[cc*4+0]);
            y[cc*4+1] = fmaf(vj, r.y, y[cc*4+1]);
            y[cc*4+2] = fmaf(vj, r.z, y[cc*4+2]);
            y[cc*4+3] = fmaf(vj, r.w, y[cc*4+3]);
        }
    }
}

__device__ __forceinline__ void read_vec(const float* M, int k, float v[32]) {
    const float4* src = (const float4*)(M + k * 32);
#pragma unroll
    for (int cc = 0; cc < 8; ++cc) {
        float4 r = src[cc];
        v[cc*4+0] = r.x; v[cc*4+1] = r.y; v[cc*4+2] = r.z; v[cc*4+3] = r.w;
    }
}

__device__ __forceinline__ void stage_vec(float* M, int k, const float v[32]) {
    float4* dst = (float4*)(M + k * 32);
#pragma unroll
    for (int cc = 0; cc < 8; ++cc)
        dst[cc] = make_float4(v[cc*4+0], v[cc*4+1], v[cc*4+2], v[cc*4+3]);
}

// out[i] (+)= sum_j (coef_j * A[k][j]) * Acol_j[i]   (A staged column-major in LDS)
template<bool ACC, bool USE_COEF>
__device__ __forceinline__ void recon32(const float* Acols, const float* coef, int k, float out[32]) {
    if (!ACC) {
#pragma unroll
        for (int i = 0; i < 32; ++i) out[i] = 0.f;
    }
    for (int j = 0; j < 32; ++j) {
        float w = Acols[j * 32 + k];          // bank k per lane: conflict-free
        if (USE_COEF) w *= coef[j];
        const float4* col = (const float4*)(Acols + j * 32);
#pragma unroll
        for (int cc = 0; cc < 8; ++cc) {
            float4 r = col[cc];
            out[cc*4+0] = fmaf(w, r.x, out[cc*4+0]);
            out[cc*4+1] = fmaf(w, r.y, out[cc*4+1]);
            out[cc*4+2] = fmaf(w, r.z, out[cc*4+2]);
            out[cc*4+3] = fmaf(w, r.w, out[cc*4+3]);
        }
    }
}

// ---------- kernels ----------

// 1a: partial batch-mean: 256 blocks, each sums 16 b's of X[4096][4096]
__global__ __launch_bounds__(256) void k_mean1(const float* __restrict__ X, float* __restrict__ part) {
    int bi = blockIdx.x;
    int tid = threadIdx.x;
    const float* xb = X + (size_t)bi * 16 * 4096;
#pragma unroll
    for (int q = 0; q < 16; ++q) {
        int e = q * 256 + tid;
        float acc = 0.f;
        for (int b = 0; b < 16; ++b) acc += xb[(size_t)b * 4096 + e];
        part[(size_t)bi * 4096 + e] = acc;
    }
}

// 1b: finish mean
__global__ __launch_bounds__(256) void k_mean2(const float* __restrict__ part, float* __restrict__ bm) {
    int e = blockIdx.x * 256 + threadIdx.x;   // 16 blocks
    float acc = 0.f;
    for (int bi = 0; bi < 256; ++bi) acc += part[(size_t)bi * 4096 + e];
    bm[e] = acc * (1.f / 4096.f);
}

// 2: eig(bm[c]) -> bm_sq, bm_isq ; eig(mean[c]) -> mean_sq.  1 block, 8 half-waves.
__global__ __launch_bounds__(256) void k_prep(const float* __restrict__ wsbm, const float* __restrict__ meang,
                                              float* __restrict__ bmsq, float* __restrict__ bmisq,
                                              float* __restrict__ msq) {
    __shared__ __align__(16) float mat[8][1024];
    __shared__ __align__(16) float aslot[8][1024];
    __shared__ float coefA[8][32];
    __shared__ float coefB[4][32];
    int tid = threadIdx.x;
    for (int i = tid; i < 4096; i += 256) {
        ((float*)mat)[i] = wsbm[i];
        ((float*)mat)[4096 + i] = meang[i];
    }
    __syncthreads();
    int hwl = tid >> 5, k = tid & 31;
    float a[32];
    read_vec(mat[hwl], k, a);
    jacobi32(a, k);
    float al = 0.f;
#pragma unroll
    for (int i = 0; i < 32; ++i) al = fmaf(a[i], a[i], al);
    al = fmaxf(al, 1e-30f);
    float lam = sqrtf(al);
    float inv_al = 1.f / al;
    if (hwl < 4) {
        float wc = fmaxf(lam, EPSC);
        float sqw = sqrtf(wc);
        coefA[hwl][k] = sqw * inv_al;            // sqrtm coef
        coefB[hwl][k] = (1.f / sqw) * inv_al;    // invsqrtm coef
    } else {
        float wc = fmaxf(lam, 0.f);
        coefA[hwl][k] = sqrtf(wc) * inv_al;      // sqrtm(mean) coef
    }
    stage_vec(aslot[hwl], k, a);
    __syncthreads();
    float o[32];
    recon32<false, true>(aslot[hwl], coefA[hwl], k, o);
    if (hwl < 4) {
        float* dst = bmsq + hwl * 1024 + k * 32;
#pragma unroll
        for (int i = 0; i < 32; ++i) dst[i] = o[i];
        recon32<false, true>(aslot[hwl], coefB[hwl], k, o);
        float* dst2 = bmisq + hwl * 1024 + k * 32;
#pragma unroll
        for (int i = 0; i < 32; ++i) dst2[i] = o[i];
    } else {
        float* dst = msq + (hwl - 4) * 1024 + k * 32;
#pragma unroll
        for (int i = 0; i < 32; ++i) dst[i] = o[i];
    }
}

// 4: pass A. Per matrix: S = bm_isq X bm_isq, eig, accumulate GT += logm(S) and
// sll += sum log^2(lambda). Deterministic block-level partials.
__global__ __launch_bounds__(256) void k_passA(const float* __restrict__ X, const float* __restrict__ bmisq_g,
                                               float* __restrict__ gtblk, float* __restrict__ sllblk) {
    __shared__ __align__(16) float bmisq[4][1024];
    __shared__ __align__(16) float slot[8][1024];
    __shared__ float coef[8][32];
    __shared__ float sllred[8][32];
    int tid = threadIdx.x;
    for (int i = tid; i < 4096; i += 256) ((float*)bmisq)[i] = bmisq_g[i];
    int hwl = tid >> 5, k = tid & 31;
    int hw = blockIdx.x * 8 + hwl;
    int c = hwl & 3;                    // == hw & 3 since 8*blockIdx = 0 mod 4
    float gt[32];
#pragma unroll
    for (int i = 0; i < 32; ++i) gt[i] = 0.f;
    float sll = 0.f;
    __syncthreads();
    for (int r = 0; r < ROUNDS; ++r) {
        int g = hw + r * NHW;
        const float4* xg = (const float4*)(X + (size_t)g * 1024);
        float4* xs = (float4*)slot[hwl];
#pragma unroll
        for (int i = 0; i < 8; ++i) xs[i * 32 + k] = xg[i * 32 + k];
        __syncthreads();
        float mk[32]; read_vec(bmisq[c], k, mk);   // col k of bm_isq (symmetric)
        float y[32];  matvec32(slot[hwl], mk, y);  // X * mk
        float a[32];  matvec32(bmisq[c], y, a);    // col k of S
        jacobi32(a, k);
        float al = 0.f;
#pragma unroll
        for (int i = 0; i < 32; ++i) al = fmaf(a[i], a[i], al);
        al = fmaxf(al, 1e-30f);
        float lam = sqrtf(al);
        float l = logf(fmaxf(lam, EPSC));
        sll = fmaf(l, l, sll);
        __syncthreads();
        stage_vec(slot[hwl], k, a);
        coef[hwl][k] = l / al;                     // log(lam)/lam^2
        __syncthreads();
        recon32<true, true>(slot[hwl], coef[hwl], k, gt);   // gt += logm(S) col k
        __syncthreads();
    }
    // pair-reduce (hwl, hwl+4): same channel
    if (hwl >= 4) stage_vec(slot[hwl], k, gt);
    sllred[hwl][k] = sll;
    __syncthreads();
    if (hwl < 4) {
        const float* p = slot[hwl + 4] + k * 32;
#pragma unroll
        for (int i = 0; i < 32; ++i) gt[i] += p[i];
        float stot = sll + sllred[hwl + 4][k];
        float* dst = gtblk + ((size_t)blockIdx.x * 4 + c) * 1024 + k * 32;
#pragma unroll
        for (int i = 0; i < 32; ++i) dst[i] = gt[i];
        sllblk[((size_t)blockIdx.x * 4 + c) * 32 + k] = stot;
    }
}

// 5a: reduce 512 block-partials -> 16 segment partials per channel
__global__ __launch_bounds__(256) void k_red(const float* __restrict__ gtblk, float* __restrict__ gt2) {
    int bi = blockIdx.x;                // 64
    int c = bi & 3, seg = bi >> 2;
    int tid = threadIdx.x;
#pragma unroll
    for (int q = 0; q < 4; ++q) {
        int e = q * 256 + tid;
        float acc = 0.f;
        for (int t = 0; t < 32; ++t) {
            int blk = seg * 32 + t;
            acc += gtblk[((size_t)blk * 4 + c) * 1024 + e];
        }
        gt2[((size_t)seg * 4 + c) * 1024 + e] = acc;
    }
}

// 5b: finish GT, batch_var, s; eig(GT) -> expm -> rm; eig(rm) -> rm_isq.
__global__ __launch_bounds__(256) void k_stats(const float* __restrict__ gt2, const float* __restrict__ sllblk,
                                               const float* __restrict__ stdg, const float* __restrict__ bmsq_g,
                                               float* __restrict__ rmisq_g, float* __restrict__ svec_g) {
    __shared__ __align__(16) float GTl[4][1024];
    __shared__ __align__(16) float bmsq[4][1024];
    __shared__ __align__(16) float slot[8][1024];
    __shared__ float coef[4][32];
    __shared__ float sred[256];
    int tid = threadIdx.x;
    for (int i = tid; i < 4096; i += 256) {
        int cc = i >> 10, e = i & 1023;
        float acc = 0.f;
        for (int seg = 0; seg < 16; ++seg) acc += gt2[((size_t)seg * 4 + cc) * 1024 + e];
        ((float*)GTl)[i] = acc * (1.f / 4096.f);
        ((float*)bmsq)[i] = bmsq_g[i];
    }
    float sacc = 0.f;
    for (int idx = tid; idx < 65536; idx += 256) sacc += sllblk[idx];  // channel (tid>>5)&3 fixed
    sred[tid] = sacc;
    __syncthreads();
    if (tid < 4) {
        float tot = 0.f;
        for (int kk = 0; kk < 32; ++kk) tot += sred[tid * 32 + kk] + sred[tid * 32 + 128 + kk];
        float sll_mean = tot * (1.f / 4096.f);
        float ssq = 0.f;
        for (int e = 0; e < 1024; ++e) { float v = GTl[tid][e]; ssq = fmaf(v, v, ssq); }
        float bvar = fmaxf(sll_mean - ssq, 0.f);     // batch_var = E||XT||^2 - ||GT||^2
        float s = stdg[tid] / sqrtf(bvar + BNEPS);
        svec_g[tid] = s;
    }
    __syncthreads();
    int hwl = tid >> 5, k = tid & 31;
    // stage 1: eig(GT) (indefinite -> Rayleigh sign), expm, rm = bm_sq expm(GT) bm_sq
    if (hwl < 4) {
        int c = hwl;
        float a[32]; read_vec(GTl[c], k, a);
        jacobi32(a, k);
        float s2 = 0.f;
#pragma unroll
        for (int i = 0; i < 32; ++i) s2 = fmaf(a[i], a[i], s2);
        s2 = fmaxf(s2, 1e-30f);
        float y[32]; matvec32(GTl[c], a, y);
        float num = 0.f;
#pragma unroll
        for (int i = 0; i < 32; ++i) num = fmaf(a[i], y[i], num);
        float rho = num / s2;                       // signed eigenvalue
        coef[hwl][k] = expf(rho) / s2;
        stage_vec(slot[hwl], k, a);
    }
    __syncthreads();
    if (hwl < 4) {
        float ex[32];
        recon32<false, true>(slot[hwl], coef[hwl], k, ex);   // expm(GT) col k
        stage_vec(slot[hwl + 4], k, ex);
    }
    __syncthreads();
    if (hwl < 4) {
        int c = hwl;
        float v1[32]; read_vec(bmsq[c], k, v1);
        float v2[32]; matvec32(slot[hwl + 4], v1, v2);
        float rmc[32]; matvec32(bmsq[c], v2, rmc);           // rm col k
        stage_vec(slot[hwl], k, rmc);
    }
    __syncthreads();
    // stage 2: eig(rm) -> rm_isq
    if (hwl < 4) {
        float a[32]; read_vec(slot[hwl], k, a);
        jacobi32(a, k);
        float al = 0.f;
#pragma unroll
        for (int i = 0; i < 32; ++i) al = fmaf(a[i], a[i], al);
        al = fmaxf(al, 1e-30f);
        float lam = sqrtf(al);
        float wc = fmaxf(lam, EPSC);
        coef[hwl][k] = (1.f / sqrtf(wc)) / al;
        stage_vec(slot[hwl], k, a);
    }
    __syncthreads();
    if (hwl < 4) {
        float o[32];
        recon32<false, true>(slot[hwl], coef[hwl], k, o);
        float* dst = rmisq_g + hwl * 1024 + k * 32;
#pragma unroll
        for (int i = 0; i < 32; ++i) dst[i] = o[i];
    }
}

// 6: pass B. inner = rm_isq X rm_isq, eig, Xn = mean_sq inner^s mean_sq = C C^T,
// C = mean_sq * (A' diag(sqrt(lam^s / lam^2)))
__global__ __launch_bounds__(256) void k_passB(const float* __restrict__ X, const float* __restrict__ rmisq_g,
                                               const float* __restrict__ msq_g, const float* __restrict__ svec_g,
                                               float* __restrict__ out) {
    __shared__ __align__(16) float rmisq[4][1024];
    __shared__ __align__(16) float msq[4][1024];
    __shared__ __align__(16) float slot[8][1024];
    __shared__ float svals[4];
    int tid = threadIdx.x;
    for (int i = tid; i < 4096; i += 256) {
        ((float*)rmisq)[i] = rmisq_g[i];
        ((float*)msq)[i] = msq_g[i];
    }
    if (tid < 4) svals[tid] = svec_g[tid];
    __syncthreads();
    int hwl = tid >> 5, k = tid & 31;
    int hw = blockIdx.x * 8 + hwl;
    int c = hwl & 3;
    for (int r = 0; r < ROUNDS; ++r) {
        int g = hw + r * NHW;
        const float4* xg = (const float4*)(X + (size_t)g * 1024);
        float4* xs = (float4*)slot[hwl];
#pragma unroll
        for (int i = 0; i < 8; ++i) xs[i * 32 + k] = xg[i * 32 + k];
        __syncthreads();
        float t1[32]; read_vec(rmisq[c], k, t1);
        float t2[32]; matvec32(slot[hwl], t1, t2);
        float a[32];  matvec32(rmisq[c], t2, a);     // inner col k
        jacobi32(a, k);
        float al = 0.f;
#pragma unroll
        for (int i = 0; i < 32; ++i) al = fmaf(a[i], a[i], al);
        al = fmaxf(al, 1e-30f);
        float lam = sqrtf(al);
        float wc = fmaxf(lam, EPSC);
        float pw = expf(svals[c] * logf(wc));        // lam^s
        float scl = sqrtf(pw / al);
        float bh[32];
#pragma unroll
        for (int i = 0; i < 32; ++i) bh[i] = a[i] * scl;
        float cc[32]; matvec32(msq[c], bh, cc);      // C col k = mean_sq * bh
        __syncthreads();
        stage_vec(slot[hwl], k, cc);
        __syncthreads();
        float xn[32];
        recon32<false, false>(slot[hwl], (const float*)nullptr, k, xn);  // Xn = C C^T col k
        float* dst = out + (size_t)g * 1024;
#pragma unroll
        for (int i = 0; i < 32; ++i) dst[i * 32 + k] = xn[i];   // coalesced across lanes
        __syncthreads();
    }
}

extern "C" void kernel_launch(void* const* d_in, const int* in_sizes, int n_in,
                              void* d_out, int out_size, void* d_ws, size_t ws_size,
                              hipStream_t stream) {
    const float* X     = (const float*)d_in[0];
    // d_in[1] running_mean, d_in[2] running_var: drop out exactly for ETA=1
    const float* meang = (const float*)d_in[3];
    const float* stdg  = (const float*)d_in[4];
    float* out = (float*)d_out;
    float* ws  = (float*)d_ws;
    (void)in_sizes; (void)n_in; (void)out_size; (void)ws_size;

    k_mean1<<<256, 256, 0, stream>>>(X, ws + OFF_PART1);
    k_mean2<<<16, 256, 0, stream>>>(ws + OFF_PART1, ws + OFF_BM);
    k_prep <<<1, 256, 0, stream>>>(ws + OFF_BM, meang, ws + OFF_BMSQ, ws + OFF_BMISQ, ws + OFF_MEANSQ);
    k_passA<<<NBLK_A, 256, 0, stream>>>(X, ws + OFF_BMISQ, ws + OFF_GTBLK, ws + OFF_SLLBLK);
    k_red  <<<64, 256, 0, stream>>>(ws + OFF_GTBLK, ws + OFF_GT2);
    k_stats<<<1, 256, 0, stream>>>(ws + OFF_GT2, ws + OFF_SLLBLK, stdg, ws + OFF_BMSQ,
                                   ws + OFF_RMISQ, ws + OFF_SVEC);
    k_passB<<<NBLK_A, 256, 0, stream>>>(X, ws + OFF_RMISQ, ws + OFF_MEANSQ, ws + OFF_SVEC, out);
}